// Round 12
// baseline (166.008 us; speedup 1.0000x reference)
//
#include <hip/hip_runtime.h>
#include <math.h>

constexpr int N  = 50000;
constexpr int E  = 800000;
constexpr int F1 = 128;
constexpr int F2 = 16;
constexpr int BSHIFT  = 8;                    // 256-node buckets
constexpr int NBUCKET = (N + 255) >> BSHIFT;  // 196
constexpr int CHUNK   = 2048;                 // edges per block in scatterP (391 blocks)
constexpr int CAP     = 6144;                 // per-bucket capacity (mean 4096, sigma 64)

typedef unsigned short ushort_t;
typedef unsigned char  uchar_t;
typedef __bf16 bf16x8 __attribute__((ext_vector_type(8)));
typedef float  f32x4  __attribute__((ext_vector_type(4)));

static __device__ __forceinline__ float blo(unsigned u) { return __uint_as_float(u << 16); }
static __device__ __forceinline__ float bhi(unsigned u) { return __uint_as_float(u & 0xffff0000u); }
static __device__ __forceinline__ ushort_t to_bf(float f) { __bf16 h = (__bf16)f; return *(ushort_t*)&h; }

// feature permutation: perm(f) = (f%16)*8 + f/16  (h1q, h1rb, W2t-K, b1p all use it)

// ---------- fused bucket scatter + weight prep ----------
__global__ __launch_bounds__(256) void k_scatterP(const int* __restrict__ row,
                                                  const int* __restrict__ col,
                                                  int* __restrict__ cursor,
                                                  unsigned* __restrict__ P,
                                                  const float* __restrict__ W1,
                                                  const float* __restrict__ W2,
                                                  const float* __restrict__ b1,
                                                  ushort_t* __restrict__ W1t,
                                                  ushort_t* __restrict__ W2t,
                                                  float* __restrict__ b1p) {
    __shared__ int hist[NBUCKET];
    __shared__ int cur[NBUCKET];
    int t = threadIdx.x;
    if (t < NBUCKET) hist[t] = 0;
    __syncthreads();
    int base = blockIdx.x * CHUNK;
#pragma unroll
    for (int i = 0; i < CHUNK / 256; ++i) {
        int e = base + i * 256 + t;
        if (e < E) atomicAdd(&hist[col[e] >> BSHIFT], 1);
    }
    __syncthreads();
    if (t < NBUCKET) cur[t] = t * CAP + atomicAdd(&cursor[t], hist[t]);
    __syncthreads();
#pragma unroll
    for (int i = 0; i < CHUNK / 256; ++i) {
        int e = base + i * 256 + t;
        if (e < E) {
            int c = col[e];
            int pos = atomicAdd(&cur[c >> BSHIFT], 1);
            P[pos] = ((unsigned)row[e] << BSHIFT) | (unsigned)(c & 255);
        }
    }

    // fused weight prep
    int gi = blockIdx.x * 256 + t;
    if (gi < F1 * F1) {                     // W1t[n][k] standard order
        int k = gi >> 7, n = gi & 127;
        W1t[n * F1 + k] = to_bf(W1[gi]);
    }
    if (gi < F1 * F2) {                     // W2t[n][perm(k)]
        int k = gi >> 4, n = gi & 15;
        int pk = (k & 15) * 8 + (k >> 4);
        W2t[n * F1 + pk] = to_bf(W2[gi]);
    }
    if (gi < F1) {                          // b1p[perm(f)] = b1[f]
        b1p[(gi & 15) * 8 + (gi >> 4)] = b1[gi];
    }
}

// ---------- per-bucket finalize ----------
__global__ __launch_bounds__(512) void k_binFinal(const unsigned* __restrict__ P,
                                                  const int* __restrict__ cursor,
                                                  ushort_t* __restrict__ csr16,
                                                  int* __restrict__ seg_start,
                                                  int* __restrict__ counts,
                                                  float* __restrict__ dinv) {
    __shared__ unsigned eb[CAP];   // 24 KB edge cache
    __shared__ int cnt[256];
    __shared__ int cur[256];
    __shared__ int wtot[4];
    int t = threadIdx.x;
    int b = blockIdx.x;
    int lo = b << BSHIFT;
    int n_nodes = min(256, N - lo);
    int m = cursor[b];
    if (t < 256) cnt[t] = 0;
    __syncthreads();
    const unsigned* Pb = P + (size_t)b * CAP;
    for (int k = t; k < m; k += 512) {
        unsigned u = Pb[k];
        eb[k] = u;
        atomicAdd(&cnt[u & 255], 1);
    }
    __syncthreads();
    int lane = t & 63, wid = t >> 6;
    int v = 0, incl = 0;
    if (t < 256) {
        v = cnt[t];
        incl = v;
#pragma unroll
        for (int d = 1; d < 64; d <<= 1) {
            int u = __shfl_up(incl, d, 64);
            if (lane >= d) incl += u;
        }
        if (lane == 63) wtot[wid] = incl;
    }
    __syncthreads();
    if (t < 256) {
        int wb = 0;
        for (int w = 0; w < wid; ++w) wb += wtot[w];
        int o = b * CAP + wb + incl - v;
        cur[t] = o;
        if (t < n_nodes) {
            seg_start[lo + t] = o;
            counts[lo + t] = v;
            dinv[lo + t] = rsqrtf((float)v + 1.f);
        }
    }
    __syncthreads();
    for (int k = t; k < m; k += 512) {
        unsigned u = eb[k];
        int pos = atomicAdd(&cur[u & 255], 1);
        csr16[pos] = (ushort_t)(u >> BSHIFT);
    }
}

// ---------- GEMM1 (MFMA bf16): h1q[perm] = fp8(dinv[r] * (x @ W1)[r]) ----------
__global__ __launch_bounds__(256) void k_gemm1_mfma(const float* __restrict__ x,
                                                    const ushort_t* __restrict__ W1t,
                                                    const float* __restrict__ dinv,
                                                    uchar_t* __restrict__ h1q) {
    __shared__ ushort_t Wl[F1 * 136];
    int t = threadIdx.x;
    for (int i = t; i < F1 * 16; i += 256) {
        int n = i >> 4, c = (i & 15) * 8;
        *(int4*)&Wl[n * 136 + c] = *(const int4*)&W1t[n * F1 + c];
    }
    __syncthreads();

    int lane = t & 63, wv = t >> 6;
    int quad = lane >> 4, l15 = lane & 15;
    int arow = blockIdx.x * 64 + wv * 16 + l15;
    int rclamp = min(arow, N - 1);
    f32x4 acc[8] = {};

#pragma unroll
    for (int kk = 0; kk < 4; ++kk) {
        int k0 = kk * 32 + quad * 8;
        const float* xp = x + (size_t)rclamp * F1 + k0;
        float4 u0 = *(const float4*)xp;
        float4 u1 = *(const float4*)(xp + 4);
        bf16x8 a;
        a[0] = (__bf16)u0.x; a[1] = (__bf16)u0.y; a[2] = (__bf16)u0.z; a[3] = (__bf16)u0.w;
        a[4] = (__bf16)u1.x; a[5] = (__bf16)u1.y; a[6] = (__bf16)u1.z; a[7] = (__bf16)u1.w;
#pragma unroll
        for (int ct = 0; ct < 8; ++ct) {
            bf16x8 b = *(const bf16x8*)&Wl[(ct * 16 + l15) * 136 + k0];
            acc[ct] = __builtin_amdgcn_mfma_f32_16x16x32_bf16(a, b, acc[ct], 0, 0, 0);
        }
    }

    // epilogue: lane l15 holds features {ct*16+l15} of row orow -> permuted bytes l15*8+ct
    int orow0 = blockIdx.x * 64 + wv * 16 + quad * 4;
#pragma unroll
    for (int r = 0; r < 4; ++r) {
        int orow = orow0 + r;
        if (orow < N) {
            float d = dinv[orow];
            unsigned d0 = __builtin_amdgcn_cvt_pk_fp8_f32(acc[0][r] * d, acc[1][r] * d, 0, false);
            d0 = __builtin_amdgcn_cvt_pk_fp8_f32(acc[2][r] * d, acc[3][r] * d, d0, true);
            unsigned d1 = __builtin_amdgcn_cvt_pk_fp8_f32(acc[4][r] * d, acc[5][r] * d, 0, false);
            d1 = __builtin_amdgcn_cvt_pk_fp8_f32(acc[6][r] * d, acc[7][r] * d, d1, true);
            uint2 pw; pw.x = d0; pw.y = d1;
            *(uint2*)(h1q + (size_t)orow * F1 + l15 * 8) = pw;
        }
    }
}

// ---------- Gather 1: one wave/node, 4 edges per wave-load ----------
// lane = q*16+sub: quarter q loads edge base+q, 8 fp8 features at sub*8 (dwordx2)
__global__ __launch_bounds__(256) void k_gather1(const uchar_t* __restrict__ h1q,
                                                 const int* __restrict__ seg_start,
                                                 const int* __restrict__ counts,
                                                 const ushort_t* __restrict__ csr16,
                                                 const float* __restrict__ dinv,
                                                 const float* __restrict__ b1p,
                                                 ushort_t* __restrict__ h1rb) {
    int c = (blockIdx.x * 256 + threadIdx.x) >> 6;
    int lane = threadIdx.x & 63;
    if (c >= N) return;
    int sub = lane & 15, q = lane >> 4;
    int s = seg_start[c], e = s + counts[c];
    float acc[8] = {0.f, 0.f, 0.f, 0.f, 0.f, 0.f, 0.f, 0.f};
    for (int base = s; base < e; base += 4) {
        int k = base + q;
        bool valid = k < e;
        int r = c;
        if (valid) r = csr16[k];                     // exec-masked load
        uint2 u = *(const uint2*)(h1q + (size_t)r * F1 + sub * 8);
        float w = valid ? 1.f : 0.f;
        acc[0] = fmaf(__builtin_amdgcn_cvt_f32_fp8(u.x, 0), w, acc[0]);
        acc[1] = fmaf(__builtin_amdgcn_cvt_f32_fp8(u.x, 1), w, acc[1]);
        acc[2] = fmaf(__builtin_amdgcn_cvt_f32_fp8(u.x, 2), w, acc[2]);
        acc[3] = fmaf(__builtin_amdgcn_cvt_f32_fp8(u.x, 3), w, acc[3]);
        acc[4] = fmaf(__builtin_amdgcn_cvt_f32_fp8(u.y, 0), w, acc[4]);
        acc[5] = fmaf(__builtin_amdgcn_cvt_f32_fp8(u.y, 1), w, acc[5]);
        acc[6] = fmaf(__builtin_amdgcn_cvt_f32_fp8(u.y, 2), w, acc[6]);
        acc[7] = fmaf(__builtin_amdgcn_cvt_f32_fp8(u.y, 3), w, acc[7]);
    }
    if (q == 0) {  // self-loop row, counted once
        uint2 u = *(const uint2*)(h1q + (size_t)c * F1 + sub * 8);
        acc[0] += __builtin_amdgcn_cvt_f32_fp8(u.x, 0);
        acc[1] += __builtin_amdgcn_cvt_f32_fp8(u.x, 1);
        acc[2] += __builtin_amdgcn_cvt_f32_fp8(u.x, 2);
        acc[3] += __builtin_amdgcn_cvt_f32_fp8(u.x, 3);
        acc[4] += __builtin_amdgcn_cvt_f32_fp8(u.y, 0);
        acc[5] += __builtin_amdgcn_cvt_f32_fp8(u.y, 1);
        acc[6] += __builtin_amdgcn_cvt_f32_fp8(u.y, 2);
        acc[7] += __builtin_amdgcn_cvt_f32_fp8(u.y, 3);
    }
    // combine quarters (lanes sub, sub+16, sub+32, sub+48 hold same features)
#pragma unroll
    for (int j = 0; j < 8; ++j) acc[j] += __shfl_xor(acc[j], 16);
#pragma unroll
    for (int j = 0; j < 8; ++j) acc[j] += __shfl_xor(acc[j], 32);
    if (q == 0) {
        float dc = dinv[c];
        float4 bb0 = ((const float4*)b1p)[sub * 2];
        float4 bb1 = ((const float4*)b1p)[sub * 2 + 1];
        float o0 = fmaxf(fmaf(dc, acc[0], bb0.x), 0.f);
        float o1 = fmaxf(fmaf(dc, acc[1], bb0.y), 0.f);
        float o2 = fmaxf(fmaf(dc, acc[2], bb0.z), 0.f);
        float o3 = fmaxf(fmaf(dc, acc[3], bb0.w), 0.f);
        float o4 = fmaxf(fmaf(dc, acc[4], bb1.x), 0.f);
        float o5 = fmaxf(fmaf(dc, acc[5], bb1.y), 0.f);
        float o6 = fmaxf(fmaf(dc, acc[6], bb1.z), 0.f);
        float o7 = fmaxf(fmaf(dc, acc[7], bb1.w), 0.f);
        int4 pw;
        pw.x = (int)((unsigned)to_bf(o0) | ((unsigned)to_bf(o1) << 16));
        pw.y = (int)((unsigned)to_bf(o2) | ((unsigned)to_bf(o3) << 16));
        pw.z = (int)((unsigned)to_bf(o4) | ((unsigned)to_bf(o5) << 16));
        pw.w = (int)((unsigned)to_bf(o6) | ((unsigned)to_bf(o7) << 16));
        *(int4*)(h1rb + (size_t)c * F1 + sub * 8) = pw;   // permuted order
    }
}

// ---------- GEMM2 (MFMA bf16): h2s = bf16(dinv[r] * (h1r @ W2)[r]) ----------
// h1rb and W2t are both K-permuted -> result unchanged
__global__ __launch_bounds__(256) void k_gemm2_mfma(const ushort_t* __restrict__ h1rb,
                                                    const ushort_t* __restrict__ W2t,
                                                    const float* __restrict__ dinv,
                                                    ushort_t* __restrict__ h2s) {
    int t = threadIdx.x, lane = t & 63, wv = t >> 6;
    int quad = lane >> 4, l15 = lane & 15;
    int arow = blockIdx.x * 64 + wv * 16 + l15;
    int rclamp = min(arow, N - 1);
    f32x4 acc = {};
#pragma unroll
    for (int kk = 0; kk < 4; ++kk) {
        int k0 = kk * 32 + quad * 8;
        bf16x8 a = *(const bf16x8*)(h1rb + (size_t)rclamp * F1 + k0);
        bf16x8 b = *(const bf16x8*)(W2t + l15 * F1 + k0);
        acc = __builtin_amdgcn_mfma_f32_16x16x32_bf16(a, b, acc, 0, 0, 0);
    }
    int orow0 = blockIdx.x * 64 + wv * 16 + quad * 4;
#pragma unroll
    for (int r = 0; r < 4; ++r) {
        int orow = orow0 + r;
        if (orow < N)
            h2s[(size_t)orow * F2 + l15] = to_bf(acc[r] * dinv[orow]);
    }
}

// ---------- Gather 2 + log_softmax: 8 lanes/node ----------
__global__ __launch_bounds__(256) void k_gather2(const ushort_t* __restrict__ h2s,
                                                 const int* __restrict__ seg_start,
                                                 const int* __restrict__ counts,
                                                 const ushort_t* __restrict__ csr16,
                                                 const float* __restrict__ dinv,
                                                 const float* __restrict__ b2,
                                                 float* __restrict__ out) {
    int idx = blockIdx.x * 256 + threadIdx.x;
    int node = idx >> 3, sub = idx & 7;
    if (node >= N) return;
    int s = seg_start[node], e = s + counts[node];
    float ax = 0.f, ay = 0.f;
    int k = s;
    for (; k + 4 <= e; k += 4) {
        int r0 = csr16[k], r1 = csr16[k + 1], r2 = csr16[k + 2], r3 = csr16[k + 3];
        unsigned u0 = ((const unsigned*)(h2s + (size_t)r0 * F2))[sub];
        unsigned u1 = ((const unsigned*)(h2s + (size_t)r1 * F2))[sub];
        unsigned u2 = ((const unsigned*)(h2s + (size_t)r2 * F2))[sub];
        unsigned u3 = ((const unsigned*)(h2s + (size_t)r3 * F2))[sub];
        ax += (blo(u0) + blo(u1)) + (blo(u2) + blo(u3));
        ay += (bhi(u0) + bhi(u1)) + (bhi(u2) + bhi(u3));
    }
    for (; k < e; ++k) {
        unsigned u = ((const unsigned*)(h2s + (size_t)csr16[k] * F2))[sub];
        ax += blo(u);
        ay += bhi(u);
    }
    unsigned us = ((const unsigned*)(h2s + (size_t)node * F2))[sub];
    ax += blo(us);
    ay += bhi(us);
    float dc = dinv[node];
    float2 bb = ((const float2*)b2)[sub];
    float v0 = fmaf(dc, ax, bb.x);
    float v1 = fmaf(dc, ay, bb.y);
    float mx = fmaxf(v0, v1);
#pragma unroll
    for (int m = 1; m < 8; m <<= 1) mx = fmaxf(mx, __shfl_xor(mx, m));
    float sm = expf(v0 - mx) + expf(v1 - mx);
#pragma unroll
    for (int m = 1; m < 8; m <<= 1) sm += __shfl_xor(sm, m);
    float lse = mx + logf(sm);
    float2 o;
    o.x = v0 - lse;
    o.y = v1 - lse;
    ((float2*)(out + (size_t)node * F2))[sub] = o;
}

extern "C" void kernel_launch(void* const* d_in, const int* in_sizes, int n_in,
                              void* d_out, int out_size, void* d_ws, size_t ws_size,
                              hipStream_t stream) {
    const float* x  = (const float*)d_in[0];
    const int*   ei = (const int*)d_in[1];
    const float* W1 = (const float*)d_in[2];
    const float* b1 = (const float*)d_in[3];
    const float* W2 = (const float*)d_in[4];
    const float* b2 = (const float*)d_in[5];
    const int* row = ei;
    const int* col = ei + E;

    char* ws = (char*)d_ws;
    int*      cursor    = (int*)ws;      ws += 256 * 4;
    unsigned* P         = (unsigned*)ws; ws += (size_t)NBUCKET * CAP * 4;
    ushort_t* csr16     = (ushort_t*)ws; ws += (size_t)(NBUCKET * CAP + 8) * 2;
    int*      seg_start = (int*)ws;      ws += (size_t)N * 4;
    int*      counts    = (int*)ws;      ws += (size_t)N * 4;
    float*    dinv      = (float*)ws;    ws += (size_t)N * 4;
    float*    b1p       = (float*)ws;    ws += (size_t)F1 * 4;
    ushort_t* W1t       = (ushort_t*)ws; ws += (size_t)F1 * F1 * 2;
    ushort_t* W2t       = (ushort_t*)ws; ws += (size_t)F2 * F1 * 2;
    uchar_t*  h1q       = (uchar_t*)ws;  ws += (size_t)N * F1;       // fp8 e4m3, permuted
    ushort_t* h1rb      = (ushort_t*)ws; ws += (size_t)N * F1 * 2;   // bf16, permuted
    ushort_t* h2s       = (ushort_t*)ws; ws += (size_t)N * F2 * 2;

    hipMemsetAsync(cursor, 0, 256 * 4, stream);

    int nbin_blocks = (E + CHUNK - 1) / CHUNK;  // 391
    k_scatterP<<<nbin_blocks, 256, 0, stream>>>(row, col, cursor, P, W1, W2, b1, W1t, W2t, b1p);
    k_binFinal<<<NBUCKET, 512, 0, stream>>>(P, cursor, csr16, seg_start, counts, dinv);

    k_gemm1_mfma<<<(N + 63) / 64, 256, 0, stream>>>(x, W1t, dinv, h1q);
    k_gather1<<<((size_t)N * 64 + 255) / 256, 256, 0, stream>>>(h1q, seg_start, counts, csr16,
                                                                dinv, b1p, h1rb);

    k_gemm2_mfma<<<(N + 63) / 64, 256, 0, stream>>>(h1rb, W2t, dinv, h2s);
    k_gather2<<<((size_t)N * 8 + 255) / 256, 256, 0, stream>>>(h2s, seg_start, counts, csr16,
                                                               dinv, b2, (float*)d_out);
}